// Round 1
// 538.629 us; speedup vs baseline: 1.1660x; 1.1660x over previous
//
#include <hip/hip_runtime.h>
#include <cstdint>

// Problem constants
#define BB   4
#define SS   1024
#define NTOK 16
#define DD   512
#define HH   8
#define HD   64
#define M_TOTAL (BB * SS * NTOK)   // 65536 rows
#define QKV_COLS (3 * HH * HD)     // 1536

typedef unsigned short u16;  // raw bf16
typedef short bf16x8 __attribute__((ext_vector_type(8)));   // 8 bf16 = 4 VGPRs
typedef float f32x4 __attribute__((ext_vector_type(4)));

__device__ __forceinline__ float bf2f(u16 u) {
  union { uint32_t i; float f; } x; x.i = ((uint32_t)u) << 16; return x.f;
}
__device__ __forceinline__ u16 f2bf(float f) {
  union { uint32_t i; float f; } x; x.f = f;
  uint32_t i = x.i;
  if ((i & 0x7fffffffu) > 0x7f800000u) return 0x7fc0;  // NaN
  uint32_t r = (i + 0x7fffu + ((i >> 16) & 1u)) >> 16; // RNE
  return (u16)r;
}

// focus_present_mask layout unknown (int32 / bool-bytes / bf16 / f32).
__device__ __forceinline__ bool decode_mask(const void* p, int b) {
  uint32_t w0 = *(const uint32_t*)p;
  if (w0 == 0x00010001u) return ((const uint8_t*)p)[b] != 0;
  if (w0 == 0x00003F80u) return ((const u16*)p)[b] != 0;
  if (w0 == 0x3F800000u) return ((const float*)p)[b] != 0.0f;
  return ((const int32_t*)p)[b] != 0;
}

// Input-dtype sniffer: flag=1 -> fp32 inputs, flag=0 -> bf16 inputs.
__global__ void sniff_kernel(const u16* __restrict__ x, int* __restrict__ flag) {
  __shared__ int any;
  if (threadIdx.x == 0) any = 0;
  __syncthreads();
  int cnt = 0;
  for (int i = threadIdx.x; i < 8192; i += 256) {
    int e = (x[i] >> 7) & 0xFF;
    if (e >= 141) cnt++;
  }
  if (cnt) atomicOr(&any, 1);
  __syncthreads();
  if (threadIdx.x == 0) *flag = any ? 1 : 0;
}

// Rotary table: cosv/sinv[n*32+i] for n in [0,16), i in [0,32).
__global__ void rot_table_kernel(float* __restrict__ cosv, float* __restrict__ sinv) {
  for (int p = threadIdx.x; p < NTOK * 32; p += 256) {
    int n = p >> 5, i = p & 31;
    float ang = (float)n * powf(10000.0f, -(float)(2 * i) / 64.0f);
    cosv[p] = cosf(ang);
    sinv[p] = sinf(ang);
  }
}

// Cast x chunk -> bf16, 4 elems/thread. elem_off = chunk start (elements).
__global__ __launch_bounds__(256) void cast_x_kernel(
    const void* __restrict__ src, u16* __restrict__ dst, size_t elem_off,
    const int* __restrict__ flag) {
  size_t i = ((size_t)blockIdx.x * 256 + threadIdx.x) * 4;
  ushort4 o;
  if (*flag) {
    float4 v = *(const float4*)((const float*)src + elem_off + i);
    o.x = f2bf(v.x); o.y = f2bf(v.y); o.z = f2bf(v.z); o.w = f2bf(v.w);
  } else {
    o = *(const ushort4*)((const u16*)src + elem_off + i);
  }
  *(ushort4*)(dst + i) = o;
}

// Cast + transpose weights: W[K][N] -> WT[N][K] bf16. One thread/element.
__global__ __launch_bounds__(256) void cast_wt_kernel(
    const void* __restrict__ W, u16* __restrict__ WT, int K, int N,
    const int* __restrict__ flag) {
  size_t idx = (size_t)blockIdx.x * 256 + threadIdx.x;  // n*K + k
  int n = (int)(idx / K), k = (int)(idx % K);
  float v = (*flag) ? ((const float*)W)[(size_t)k * N + n]
                    : bf2f(((const u16*)W)[(size_t)k * N + n]);
  WT[idx] = f2bf(v);
}

// ---------------------------------------------------------------------------
// MFMA GEMM (m97 structure): C[M,N] = A[M,K] @ BT[N,K]^T, bf16 in, fp32 acc.
// 128x128 tile, BK=32, 256 threads = 4 waves, each 64x64 (4x4 16x16x32 frags).
// global_load_lds width=16 staging; XOR chunk swizzle cuts read conflicts.
// OUT_F32: 1 -> C fp32 when *flag (final output), else bf16.
// ---------------------------------------------------------------------------
template <int OUT_F32>
__global__ __launch_bounds__(256) void gemm_mfma_bt(
    const u16* __restrict__ A, const u16* __restrict__ BT, void* __restrict__ Cbase,
    size_t c_elem_off, int M, int N, int K, const int* __restrict__ flag) {
  __shared__ u16 Asl[128 * 32];
  __shared__ u16 Bsl[128 * 32];
  const int tid  = threadIdx.x;
  const int wave = tid >> 6;
  const int lane = tid & 63;
  const int bm = blockIdx.y * 128;
  const int bn = blockIdx.x * 128;
  const int wm = (wave >> 1) * 64;
  const int wn = (wave & 1) * 64;
  const int m_lane = lane & 15;
  const int kgrp   = lane >> 4;

  f32x4 acc[4][4];
#pragma unroll
  for (int r = 0; r < 4; ++r)
#pragma unroll
    for (int c = 0; c < 4; ++c) acc[r][c] = (f32x4){0.f, 0.f, 0.f, 0.f};

  for (int k0 = 0; k0 < K; k0 += 32) {
#pragma unroll
    for (int q = 0; q < 2; ++q) {
      const int idx = q * 256 + tid;          // LDS slot 0..511 (16 B each)
      const int row = idx >> 2;               // tile row 0..127
      const int gc  = (idx & 3) ^ (row & 3);  // swizzled global 16B chunk
      const u16* ga = A  + (size_t)(bm + row) * K + k0 + gc * 8;
      const u16* gb = BT + (size_t)(bn + row) * K + k0 + gc * 8;
      u16* la = Asl + (size_t)(q * 256 + wave * 64) * 8;  // wave-uniform base
      u16* lb = Bsl + (size_t)(q * 256 + wave * 64) * 8;
      __builtin_amdgcn_global_load_lds(
          (const __attribute__((address_space(1))) void*)ga,
          (__attribute__((address_space(3))) void*)la, 16, 0, 0);
      __builtin_amdgcn_global_load_lds(
          (const __attribute__((address_space(1))) void*)gb,
          (__attribute__((address_space(3))) void*)lb, 16, 0, 0);
    }
    __syncthreads();

    bf16x8 af[4], bfr[4];
#pragma unroll
    for (int r = 0; r < 4; ++r) {
      const int ra = wm + r * 16 + m_lane;
      af[r] = *(const bf16x8*)(Asl + ra * 32 + ((kgrp ^ (ra & 3)) * 8));
    }
#pragma unroll
    for (int c = 0; c < 4; ++c) {
      const int rb = wn + c * 16 + m_lane;
      bfr[c] = *(const bf16x8*)(Bsl + rb * 32 + ((kgrp ^ (rb & 3)) * 8));
    }
#pragma unroll
    for (int r = 0; r < 4; ++r)
#pragma unroll
      for (int c = 0; c < 4; ++c)
        acc[r][c] = __builtin_amdgcn_mfma_f32_16x16x32_bf16(af[r], bfr[c], acc[r][c], 0, 0, 0);
    __syncthreads();
  }

  // C/D layout (m89): col = lane&15, row = (lane>>4)*4 + j
  const bool f32out = OUT_F32 && (*flag != 0);
#pragma unroll
  for (int r = 0; r < 4; ++r) {
    const int grow0 = bm + wm + r * 16 + kgrp * 4;
#pragma unroll
    for (int c = 0; c < 4; ++c) {
      const int gcol = bn + wn + c * 16 + m_lane;
#pragma unroll
      for (int j = 0; j < 4; ++j) {
        const size_t off = c_elem_off + (size_t)(grow0 + j) * N + gcol;
        if (f32out) ((float*)Cbase)[off] = acc[r][c][j];
        else        ((u16*)Cbase)[off]   = f2bf(acc[r][c][j]);
      }
    }
  }
}

// ---------------------------------------------------------------------------
// Attention v2: one WAVE per (bs_local, h). N=16 tokens = one 16x16 MFMA tile.
//   simT = mfma(K_frag, Q_frag)  -> lane holds sim[qt=lane&15][kt=(lane>>4)*4+j]
//   row softmax = 3 local ops + shfl_xor(16) + shfl_xor(32)  (all 64 lanes)
//   outT = mfma(V^T_frag, P_frag) per 16-dim tile (K padded 16->32)
// No per-wave barriers; single block barrier for cos/sin LDS staging.
// ---------------------------------------------------------------------------
__global__ __launch_bounds__(256) void attn_kernel(
    const u16* __restrict__ qkv, const void* __restrict__ pos_bias,
    const void* __restrict__ maskp, u16* __restrict__ attno, int bs0,
    const float* __restrict__ cosv, const float* __restrict__ sinv,
    const int* __restrict__ flag) {
  __shared__ float lcos[NTOK * 33];
  __shared__ float lsin[NTOK * 33];
  const int tid = threadIdx.x;
  for (int p = tid; p < NTOK * 32; p += 256) {
    int n = p >> 5, i = p & 31;
    lcos[n * 33 + i] = cosv[p];
    lsin[n * 33 + i] = sinv[p];
  }
  __syncthreads();

  const int wave = tid >> 6;
  const int lane = tid & 63;
  const int wid = blockIdx.x * 4 + wave;   // global (bsl, h) index
  const int bsl = wid >> 3;
  const int h = wid & (HH - 1);
  const int b = (bs0 + bsl) >> 10;
  const int qt = lane & 15;    // token row of this lane's fragments
  const int kg = lane >> 4;    // k-group 0..3

  // ---- Q/K fragment loads: lane holds token qt, dims kg*8..+7 and +32 ----
  const u16* rowp = qkv + ((size_t)bsl * NTOK + qt) * QKV_COLS + h * HD;
  float qv[16], kv[16];
#pragma unroll
  for (int hf = 0; hf < 2; ++hf) {
    const bf16x8 uq = *(const bf16x8*)(rowp + hf * 32 + kg * 8);
    const bf16x8 uk = *(const bf16x8*)(rowp + 512 + hf * 32 + kg * 8);
#pragma unroll
    for (int t = 0; t < 8; ++t) {
      qv[hf * 8 + t] = bf2f((u16)uq[t]);
      kv[hf * 8 + t] = bf2f((u16)uk[t]);
    }
  }

  // ---- V fragment scalar loads (L2-hot), issued early to hide latency ----
  // A-frag for outT: lane needs V[k = kg*8+t][dim = mt*16 + qt], zeros kg>=2.
  const u16* vbase = qkv + (size_t)bsl * NTOK * QKV_COLS + 1024 + h * HD;
  u16 vraw[32];
#pragma unroll
  for (int mt = 0; mt < 4; ++mt)
#pragma unroll
    for (int t = 0; t < 8; ++t)
      vraw[mt * 8 + t] = (kg < 2)
          ? vbase[(size_t)(kg * 8 + t) * QKV_COLS + mt * 16 + qt]
          : (u16)0;

  // ---- rotary in-register (f32), q scaled by 1/8, repack bf16 ----
  bf16x8 qa[2], ka[2];
#pragma unroll
  for (int hf = 0; hf < 2; ++hf) {
#pragma unroll
    for (int t = 0; t < 4; ++t) {
      const int idx = qt * 33 + hf * 16 + kg * 4 + t;
      const float cth = lcos[idx], sth = lsin[idx];
      const int e0 = hf * 8 + 2 * t, e1 = e0 + 1;
      const float q0 = qv[e0], q1 = qv[e1];
      qa[hf][2 * t]     = (short)f2bf((q0 * cth - q1 * sth) * 0.125f);
      qa[hf][2 * t + 1] = (short)f2bf((q1 * cth + q0 * sth) * 0.125f);
      const float k0 = kv[e0], k1 = kv[e1];
      ka[hf][2 * t]     = (short)f2bf(k0 * cth - k1 * sth);
      ka[hf][2 * t + 1] = (short)f2bf(k1 * cth + k0 * sth);
    }
  }

  // ---- simT = K @ Q^T : lane holds sim[qt][kt=kg*4+j], j=0..3 ----
  f32x4 cacc = (f32x4){0.f, 0.f, 0.f, 0.f};
  cacc = __builtin_amdgcn_mfma_f32_16x16x32_bf16(ka[0], qa[0], cacc, 0, 0, 0);
  cacc = __builtin_amdgcn_mfma_f32_16x16x32_bf16(ka[1], qa[1], cacc, 0, 0, 0);

  // ---- pos_bias + mask ----
  const bool f32pb = (*flag != 0);
  const bool focus = decode_mask(maskp, b);
  float sv[4];
#pragma unroll
  for (int j = 0; j < 4; ++j) {
    const int kt = kg * 4 + j;
    const size_t pbidx = ((size_t)h * NTOK + qt) * NTOK + kt;
    const float pb = f32pb ? ((const float*)pos_bias)[pbidx]
                           : bf2f(((const u16*)pos_bias)[pbidx]);
    float v = cacc[j] + pb;
    if (focus && (qt != kt)) v = -3.0e38f;
    sv[j] = v;
  }

  // ---- row softmax: local over j, then xor-16 / xor-32 across k-groups ----
  float m = fmaxf(fmaxf(sv[0], sv[1]), fmaxf(sv[2], sv[3]));
  m = fmaxf(m, __shfl_xor(m, 16, 64));
  m = fmaxf(m, __shfl_xor(m, 32, 64));
  float pj[4];
  float ssum = 0.f;
#pragma unroll
  for (int j = 0; j < 4; ++j) {
    pj[j] = expf(sv[j] - m);
    ssum += pj[j];
  }
  ssum += __shfl_xor(ssum, 16, 64);
  ssum += __shfl_xor(ssum, 32, 64);
  const float inv = 1.0f / ssum;
#pragma unroll
  for (int j = 0; j < 4; ++j) pj[j] *= inv;

  // ---- build P fragment: lane needs P[qt][kg*8+t], zeros for kg>=2 ----
  bf16x8 pfrag;
#pragma unroll
  for (int t = 0; t < 8; ++t) {
    const int src = (lane & 15) + (((kg << 1) + (t >> 2)) << 4);
    const float v = __shfl(pj[t & 3], src & 63, 64);
    pfrag[t] = (kg < 2) ? (short)f2bf(v) : (short)0;
  }

  // ---- outT = V^T @ P^T per 16-dim tile; coalesced ushort4 stores ----
  u16* orow = attno + ((size_t)bsl * NTOK + qt) * (HH * HD) + h * HD;
#pragma unroll
  for (int mt = 0; mt < 4; ++mt) {
    bf16x8 vfrag;
#pragma unroll
    for (int t = 0; t < 8; ++t) vfrag[t] = (short)vraw[mt * 8 + t];
    f32x4 o = (f32x4){0.f, 0.f, 0.f, 0.f};
    o = __builtin_amdgcn_mfma_f32_16x16x32_bf16(vfrag, pfrag, o, 0, 0, 0);
    ushort4 uo;
    uo.x = f2bf(o[0]); uo.y = f2bf(o[1]); uo.z = f2bf(o[2]); uo.w = f2bf(o[3]);
    *(ushort4*)(orow + mt * 16 + kg * 4) = uo;
  }
}

extern "C" void kernel_launch(void* const* d_in, const int* in_sizes, int n_in,
                              void* d_out, int out_size, void* d_ws, size_t ws_size,
                              hipStream_t stream) {
  const void* x_raw    = d_in[0];  // (65536, 512)
  const void* pos_bias = d_in[1];  // (8,16,16)
  const void* W_qkv    = d_in[2];  // (512,1536)
  const void* W_out    = d_in[3];  // (512,512)
  const void* maskp    = d_in[4];  // (4,)

  char* ws = (char*)d_ws;
  int*   flag = (int*)ws;                          // 256 B
  float* cosv = (float*)(ws + 256);                // 2 KB
  float* sinv = cosv + NTOK * 32;                  // 2 KB
  u16* WqT = (u16*)(ws + 256 + 4096);              // 1536x512 bf16
  u16* WoT = WqT + (size_t)QKV_COLS * DD;          // 512x512 bf16
  u16* scratch = WoT + (size_t)DD * DD;
  const size_t fixed = 256 + 4096 + (size_t)QKV_COLS * DD * 2 + (size_t)DD * DD * 2;
  const size_t ws_avail = (ws_size > fixed) ? ws_size - fixed : 0;

  // per chunk: xb rows*1024 + qkv rows*3072 + attno rows*1024 = 5120 B/row
  const size_t per_row = 5120;
  int chunk_rows = M_TOTAL;
  while ((size_t)chunk_rows * per_row > ws_avail && chunk_rows > 128) chunk_rows >>= 1;
  const int nchunks = M_TOTAL / chunk_rows;

  u16* xb    = scratch;                                   // chunk x 512  bf16
  u16* qkv   = xb  + (size_t)chunk_rows * DD;             // chunk x 1536 bf16
  u16* attno = qkv + (size_t)chunk_rows * QKV_COLS;       // chunk x 512  bf16

  sniff_kernel<<<1, 256, 0, stream>>>((const u16*)x_raw, flag);
  rot_table_kernel<<<1, 256, 0, stream>>>(cosv, sinv);
  cast_wt_kernel<<<(QKV_COLS * DD) / 256, 256, 0, stream>>>(W_qkv, WqT, DD, QKV_COLS, flag);
  cast_wt_kernel<<<(DD * DD) / 256, 256, 0, stream>>>(W_out, WoT, DD, DD, flag);

  for (int c = 0; c < nchunks; ++c) {
    const int bs0 = c * (chunk_rows / NTOK);
    const size_t eoff = (size_t)c * chunk_rows * DD;   // element offset in x / out

    cast_x_kernel<<<(int)(((size_t)chunk_rows * DD) / 1024), 256, 0, stream>>>(
        x_raw, xb, eoff, flag);

    {  // 1) qkv = xb @ WqT^T
      dim3 grid(QKV_COLS / 128, chunk_rows / 128);
      gemm_mfma_bt<0><<<grid, 256, 0, stream>>>(xb, WqT, (void*)qkv, 0,
                                                chunk_rows, QKV_COLS, DD, flag);
    }
    {  // 2) attention: one wave per (bsl, h), 4 waves per block
      dim3 grid(((chunk_rows / NTOK) * HH) / 4);
      attn_kernel<<<grid, 256, 0, stream>>>(qkv, pos_bias, maskp, attno, bs0,
                                            cosv, sinv, flag);
    }
    {  // 3) out = attno @ WoT^T  (fp32 out when flag=1, else bf16)
      dim3 grid(DD / 128, chunk_rows / 128);
      gemm_mfma_bt<1><<<grid, 256, 0, stream>>>(attno, WoT, d_out, eoff,
                                                chunk_rows, DD, DD, flag);
    }
  }
}

// Round 2
// 524.080 us; speedup vs baseline: 1.1984x; 1.0278x over previous
//
#include <hip/hip_runtime.h>
#include <cstdint>

// Problem constants
#define BB   4
#define SS   1024
#define NTOK 16
#define DD   512
#define HH   8
#define HD   64
#define M_TOTAL (BB * SS * NTOK)   // 65536 rows
#define QKV_COLS (3 * HH * HD)     // 1536

typedef unsigned short u16;  // raw bf16
typedef short bf16x8 __attribute__((ext_vector_type(8)));   // 8 bf16 = 4 VGPRs
typedef float f32x4 __attribute__((ext_vector_type(4)));

__device__ __forceinline__ float bf2f(u16 u) {
  union { uint32_t i; float f; } x; x.i = ((uint32_t)u) << 16; return x.f;
}
__device__ __forceinline__ u16 f2bf(float f) {
  union { uint32_t i; float f; } x; x.f = f;
  uint32_t i = x.i;
  if ((i & 0x7fffffffu) > 0x7f800000u) return 0x7fc0;  // NaN
  uint32_t r = (i + 0x7fffu + ((i >> 16) & 1u)) >> 16; // RNE
  return (u16)r;
}

// focus_present_mask layout unknown (int32 / bool-bytes / bf16 / f32).
__device__ __forceinline__ bool decode_mask(const void* p, int b) {
  uint32_t w0 = *(const uint32_t*)p;
  if (w0 == 0x00010001u) return ((const uint8_t*)p)[b] != 0;
  if (w0 == 0x00003F80u) return ((const u16*)p)[b] != 0;
  if (w0 == 0x3F800000u) return ((const float*)p)[b] != 0.0f;
  return ((const int32_t*)p)[b] != 0;
}

// Input-dtype sniffer: flag=1 -> fp32 inputs, flag=0 -> bf16 inputs.
__global__ void sniff_kernel(const u16* __restrict__ x, int* __restrict__ flag) {
  __shared__ int any;
  if (threadIdx.x == 0) any = 0;
  __syncthreads();
  int cnt = 0;
  for (int i = threadIdx.x; i < 8192; i += 256) {
    int e = (x[i] >> 7) & 0xFF;
    if (e >= 141) cnt++;
  }
  if (cnt) atomicOr(&any, 1);
  __syncthreads();
  if (threadIdx.x == 0) *flag = any ? 1 : 0;
}

// Rotary table: cosv/sinv[n*32+i] for n in [0,16), i in [0,32).
__global__ void rot_table_kernel(float* __restrict__ cosv, float* __restrict__ sinv) {
  for (int p = threadIdx.x; p < NTOK * 32; p += 256) {
    int n = p >> 5, i = p & 31;
    float ang = (float)n * powf(10000.0f, -(float)(2 * i) / 64.0f);
    cosv[p] = cosf(ang);
    sinv[p] = sinf(ang);
  }
}

// Cast x chunk -> bf16, 4 elems/thread. elem_off = chunk start (elements).
__global__ __launch_bounds__(256) void cast_x_kernel(
    const void* __restrict__ src, u16* __restrict__ dst, size_t elem_off,
    const int* __restrict__ flag) {
  size_t i = ((size_t)blockIdx.x * 256 + threadIdx.x) * 4;
  ushort4 o;
  if (*flag) {
    float4 v = *(const float4*)((const float*)src + elem_off + i);
    o.x = f2bf(v.x); o.y = f2bf(v.y); o.z = f2bf(v.z); o.w = f2bf(v.w);
  } else {
    o = *(const ushort4*)((const u16*)src + elem_off + i);
  }
  *(ushort4*)(dst + i) = o;
}

// Cast + transpose weights: W[K][N] -> WT[N][K] bf16. One thread/element.
__global__ __launch_bounds__(256) void cast_wt_kernel(
    const void* __restrict__ W, u16* __restrict__ WT, int K, int N,
    const int* __restrict__ flag) {
  size_t idx = (size_t)blockIdx.x * 256 + threadIdx.x;  // n*K + k
  int n = (int)(idx / K), k = (int)(idx % K);
  float v = (*flag) ? ((const float*)W)[(size_t)k * N + n]
                    : bf2f(((const u16*)W)[(size_t)k * N + n]);
  WT[idx] = f2bf(v);
}

// ---------------------------------------------------------------------------
// 256x256 8-phase MFMA GEMM (m201-style): C[M,N] = A[M,K] @ BT[N,K]^T.
// 512 thr = 8 waves (2M x 4N), per-wave 128x64 = acc[8][4] 16x16 frags.
// BK=64 split in 2 K-halves; LDS [2 buf][2 kh][256 rows][32 k] bf16 (128 KiB).
//   * 64B LDS rows -> ds_read_b128 frag pattern is bank-balanced (no swizzle,
//     both sides linear => rule-21 safe with global_load_lds).
// Phase/K-tile u (buf b=u&1): P1{dsread A(mh0,ks0)+B(ks0); stage A-kh0(u+1)},
//   P2{dsread A(mh1,ks0); stage B-kh0(u+1); vmcnt(4)}, P3{A(mh0,ks1)+B(ks1);
//   stage A-kh1(u+1)}, P4{A(mh1,ks1); stage B-kh1(u+1); vmcnt(4)}.
// vmcnt ledger: at each wait 8 loads outstanding, oldest 4 = units needed one
// phase later; never drained to 0 mid-loop (tail tile waits vmcnt(0)).
// Raw s_barrier + sched_barrier(0); setprio(1) around each 16-MFMA cluster.
// ---------------------------------------------------------------------------
template <int OUT_F32>
__global__ __launch_bounds__(512, 2) void gemm_mfma_bt256(
    const u16* __restrict__ A, const u16* __restrict__ BT, void* __restrict__ Cbase,
    size_t c_elem_off, int M, int N, int K, const int* __restrict__ flag) {
  __shared__ u16 As[2][2][256 * 32];
  __shared__ u16 Bs[2][2][256 * 32];
  const int tid  = threadIdx.x;
  const int wave = tid >> 6;
  const int lane = tid & 63;
  const int wr = wave >> 2;      // 0..1 (M)
  const int wc = wave & 3;       // 0..3 (N)
  const int m_lane = lane & 15;
  const int kgrp   = lane >> 4;

  // Bijective XCD-aware block swizzle (m204), row-major within chunk.
  const int nwg = (int)gridDim.x;
  const int bid = (int)blockIdx.x;
  const int q8 = nwg >> 3, r8 = nwg & 7;
  const int xcd = bid & 7;
  const int swz = ((xcd < r8) ? xcd * (q8 + 1) : r8 * (q8 + 1) + (xcd - r8) * q8)
                  + (bid >> 3);
  const int nbn = N >> 8;
  const int bm = (swz / nbn) << 8;
  const int bn = (swz % nbn) << 8;

  const u16* Ag = A  + (size_t)bm * K;
  const u16* Bg = BT + (size_t)bn * K;

  f32x4 acc[8][4];
#pragma unroll
  for (int m = 0; m < 8; ++m)
#pragma unroll
    for (int n = 0; n < 4; ++n) acc[m][n] = (f32x4){0.f, 0.f, 0.f, 0.f};

  // Stage one K-half unit (256 rows x 32 k) = 2 x global_load_lds / thread.
  auto stage = [&](const u16* gbase, int tile, int kh, u16* lbase) {
#pragma unroll
    for (int l = 0; l < 2; ++l) {
      const int slot = l * 512 + tid;                 // 0..1023 (16B chunks)
      const u16* ga = gbase + (size_t)(slot >> 2) * K + tile * 64 + kh * 32
                      + (slot & 3) * 8;
      u16* la = lbase + (size_t)(l * 512 + wave * 64) * 8;  // wave-uniform base
      __builtin_amdgcn_global_load_lds(
          (const __attribute__((address_space(1))) void*)ga,
          (__attribute__((address_space(3))) void*)la, 16, 0, 0);
    }
  };

  const int nt = K >> 6;

  // Prologue: tile 0 into buf 0; order A-kh0,B-kh0,A-kh1,B-kh1 so that
  // vmcnt(4) leaves the kh1 units (needed at P3) in flight.
  stage(Ag, 0, 0, As[0][0]);
  stage(Bg, 0, 0, Bs[0][0]);
  stage(Ag, 0, 1, As[0][1]);
  stage(Bg, 0, 1, Bs[0][1]);
  asm volatile("s_waitcnt vmcnt(4)" ::: "memory");
  __builtin_amdgcn_s_barrier();
  __builtin_amdgcn_sched_barrier(0);

  for (int u = 0; u < nt; ++u) {
    const int b = u & 1, nb = b ^ 1;
    const bool pf = (u + 1 < nt);
    bf16x8 af[4], bfr[4];
#pragma unroll
    for (int ks = 0; ks < 2; ++ks) {
      // ---- phase A (mh=0): 4xA + 4xB ds_read_b128, stage A-kh{ks}(u+1) ----
#pragma unroll
      for (int m = 0; m < 4; ++m)
        af[m] = *(const bf16x8*)&As[b][ks][(wr * 128 + m * 16 + m_lane) * 32 + kgrp * 8];
#pragma unroll
      for (int n = 0; n < 4; ++n)
        bfr[n] = *(const bf16x8*)&Bs[b][ks][(wc * 64 + n * 16 + m_lane) * 32 + kgrp * 8];
      if (pf) stage(Ag, u + 1, ks, As[nb][ks]);
      __builtin_amdgcn_s_barrier();
      __builtin_amdgcn_sched_barrier(0);
      __builtin_amdgcn_s_setprio(1);
#pragma unroll
      for (int m = 0; m < 4; ++m)
#pragma unroll
        for (int n = 0; n < 4; ++n)
          acc[m][n] = __builtin_amdgcn_mfma_f32_16x16x32_bf16(af[m], bfr[n], acc[m][n], 0, 0, 0);
      __builtin_amdgcn_s_setprio(0);
      __builtin_amdgcn_s_barrier();
      __builtin_amdgcn_sched_barrier(0);

      // ---- phase B (mh=1): 4xA ds_read, stage B-kh{ks}(u+1), counted wait --
#pragma unroll
      for (int m = 0; m < 4; ++m)
        af[m] = *(const bf16x8*)&As[b][ks][(wr * 128 + (m + 4) * 16 + m_lane) * 32 + kgrp * 8];
      if (pf) stage(Bg, u + 1, ks, Bs[nb][ks]);
      if (pf) asm volatile("s_waitcnt vmcnt(4)" ::: "memory");
      else    asm volatile("s_waitcnt vmcnt(0)" ::: "memory");
      __builtin_amdgcn_s_barrier();
      __builtin_amdgcn_sched_barrier(0);
      __builtin_amdgcn_s_setprio(1);
#pragma unroll
      for (int m = 0; m < 4; ++m)
#pragma unroll
        for (int n = 0; n < 4; ++n)
          acc[m + 4][n] = __builtin_amdgcn_mfma_f32_16x16x32_bf16(af[m], bfr[n], acc[m + 4][n], 0, 0, 0);
      __builtin_amdgcn_s_setprio(0);
      __builtin_amdgcn_s_barrier();
      __builtin_amdgcn_sched_barrier(0);
    }
  }

  // C/D layout (m89): col = lane&15, row = (lane>>4)*4 + j
  const bool f32out = OUT_F32 && (*flag != 0);
#pragma unroll
  for (int m = 0; m < 8; ++m) {
    const int grow0 = bm + wr * 128 + m * 16 + kgrp * 4;
#pragma unroll
    for (int n = 0; n < 4; ++n) {
      const int gcol = bn + wc * 64 + n * 16 + m_lane;
#pragma unroll
      for (int j = 0; j < 4; ++j) {
        const size_t off = c_elem_off + (size_t)(grow0 + j) * N + gcol;
        if (f32out) ((float*)Cbase)[off] = acc[m][n][j];
        else        ((u16*)Cbase)[off]   = f2bf(acc[m][n][j]);
      }
    }
  }
}

// ---------------------------------------------------------------------------
// Attention: one WAVE per (bs_local, h). N=16 tokens = one 16x16 MFMA tile.
//   simT = mfma(K_frag, Q_frag); row softmax via 2 shfl_xor; outT = V^T @ P^T.
// ---------------------------------------------------------------------------
__global__ __launch_bounds__(256) void attn_kernel(
    const u16* __restrict__ qkv, const void* __restrict__ pos_bias,
    const void* __restrict__ maskp, u16* __restrict__ attno, int bs0,
    const float* __restrict__ cosv, const float* __restrict__ sinv,
    const int* __restrict__ flag) {
  __shared__ float lcos[NTOK * 33];
  __shared__ float lsin[NTOK * 33];
  const int tid = threadIdx.x;
  for (int p = tid; p < NTOK * 32; p += 256) {
    int n = p >> 5, i = p & 31;
    lcos[n * 33 + i] = cosv[p];
    lsin[n * 33 + i] = sinv[p];
  }
  __syncthreads();

  const int wave = tid >> 6;
  const int lane = tid & 63;
  const int wid = blockIdx.x * 4 + wave;   // global (bsl, h) index
  const int bsl = wid >> 3;
  const int h = wid & (HH - 1);
  const int b = (bs0 + bsl) >> 10;
  const int qt = lane & 15;    // token row of this lane's fragments
  const int kg = lane >> 4;    // k-group 0..3

  // ---- Q/K fragment loads: lane holds token qt, dims kg*8..+7 and +32 ----
  const u16* rowp = qkv + ((size_t)bsl * NTOK + qt) * QKV_COLS + h * HD;
  float qv[16], kv[16];
#pragma unroll
  for (int hf = 0; hf < 2; ++hf) {
    const bf16x8 uq = *(const bf16x8*)(rowp + hf * 32 + kg * 8);
    const bf16x8 uk = *(const bf16x8*)(rowp + 512 + hf * 32 + kg * 8);
#pragma unroll
    for (int t = 0; t < 8; ++t) {
      qv[hf * 8 + t] = bf2f((u16)uq[t]);
      kv[hf * 8 + t] = bf2f((u16)uk[t]);
    }
  }

  // ---- V fragment scalar loads (L2-hot), issued early to hide latency ----
  const u16* vbase = qkv + (size_t)bsl * NTOK * QKV_COLS + 1024 + h * HD;
  u16 vraw[32];
#pragma unroll
  for (int mt = 0; mt < 4; ++mt)
#pragma unroll
    for (int t = 0; t < 8; ++t)
      vraw[mt * 8 + t] = (kg < 2)
          ? vbase[(size_t)(kg * 8 + t) * QKV_COLS + mt * 16 + qt]
          : (u16)0;

  // ---- rotary in-register (f32), q scaled by 1/8, repack bf16 ----
  bf16x8 qa[2], ka[2];
#pragma unroll
  for (int hf = 0; hf < 2; ++hf) {
#pragma unroll
    for (int t = 0; t < 4; ++t) {
      const int idx = qt * 33 + hf * 16 + kg * 4 + t;
      const float cth = lcos[idx], sth = lsin[idx];
      const int e0 = hf * 8 + 2 * t, e1 = e0 + 1;
      const float q0 = qv[e0], q1 = qv[e1];
      qa[hf][2 * t]     = (short)f2bf((q0 * cth - q1 * sth) * 0.125f);
      qa[hf][2 * t + 1] = (short)f2bf((q1 * cth + q0 * sth) * 0.125f);
      const float k0 = kv[e0], k1 = kv[e1];
      ka[hf][2 * t]     = (short)f2bf(k0 * cth - k1 * sth);
      ka[hf][2 * t + 1] = (short)f2bf(k1 * cth + k0 * sth);
    }
  }

  // ---- simT = K @ Q^T : lane holds sim[qt][kt=kg*4+j], j=0..3 ----
  f32x4 cacc = (f32x4){0.f, 0.f, 0.f, 0.f};
  cacc = __builtin_amdgcn_mfma_f32_16x16x32_bf16(ka[0], qa[0], cacc, 0, 0, 0);
  cacc = __builtin_amdgcn_mfma_f32_16x16x32_bf16(ka[1], qa[1], cacc, 0, 0, 0);

  // ---- pos_bias + mask ----
  const bool f32pb = (*flag != 0);
  const bool focus = decode_mask(maskp, b);
  float sv[4];
#pragma unroll
  for (int j = 0; j < 4; ++j) {
    const int kt = kg * 4 + j;
    const size_t pbidx = ((size_t)h * NTOK + qt) * NTOK + kt;
    const float pb = f32pb ? ((const float*)pos_bias)[pbidx]
                           : bf2f(((const u16*)pos_bias)[pbidx]);
    float v = cacc[j] + pb;
    if (focus && (qt != kt)) v = -3.0e38f;
    sv[j] = v;
  }

  // ---- row softmax: local over j, then xor-16 / xor-32 across k-groups ----
  float m = fmaxf(fmaxf(sv[0], sv[1]), fmaxf(sv[2], sv[3]));
  m = fmaxf(m, __shfl_xor(m, 16, 64));
  m = fmaxf(m, __shfl_xor(m, 32, 64));
  float pj[4];
  float ssum = 0.f;
#pragma unroll
  for (int j = 0; j < 4; ++j) {
    pj[j] = expf(sv[j] - m);
    ssum += pj[j];
  }
  ssum += __shfl_xor(ssum, 16, 64);
  ssum += __shfl_xor(ssum, 32, 64);
  const float inv = 1.0f / ssum;
#pragma unroll
  for (int j = 0; j < 4; ++j) pj[j] *= inv;

  // ---- build P fragment: lane needs P[qt][kg*8+t], zeros for kg>=2 ----
  bf16x8 pfrag;
#pragma unroll
  for (int t = 0; t < 8; ++t) {
    const int src = (lane & 15) + (((kg << 1) + (t >> 2)) << 4);
    const float v = __shfl(pj[t & 3], src & 63, 64);
    pfrag[t] = (kg < 2) ? (short)f2bf(v) : (short)0;
  }

  // ---- outT = V^T @ P^T per 16-dim tile; coalesced ushort4 stores ----
  u16* orow = attno + ((size_t)bsl * NTOK + qt) * (HH * HD) + h * HD;
#pragma unroll
  for (int mt = 0; mt < 4; ++mt) {
    bf16x8 vfrag;
#pragma unroll
    for (int t = 0; t < 8; ++t) vfrag[t] = (short)vraw[mt * 8 + t];
    f32x4 o = (f32x4){0.f, 0.f, 0.f, 0.f};
    o = __builtin_amdgcn_mfma_f32_16x16x32_bf16(vfrag, pfrag, o, 0, 0, 0);
    ushort4 uo;
    uo.x = f2bf(o[0]); uo.y = f2bf(o[1]); uo.z = f2bf(o[2]); uo.w = f2bf(o[3]);
    *(ushort4*)(orow + mt * 16 + kg * 4) = uo;
  }
}

extern "C" void kernel_launch(void* const* d_in, const int* in_sizes, int n_in,
                              void* d_out, int out_size, void* d_ws, size_t ws_size,
                              hipStream_t stream) {
  const void* x_raw    = d_in[0];  // (65536, 512)
  const void* pos_bias = d_in[1];  // (8,16,16)
  const void* W_qkv    = d_in[2];  // (512,1536)
  const void* W_out    = d_in[3];  // (512,512)
  const void* maskp    = d_in[4];  // (4,)

  char* ws = (char*)d_ws;
  int*   flag = (int*)ws;                          // 256 B
  float* cosv = (float*)(ws + 256);                // 2 KB
  float* sinv = cosv + NTOK * 32;                  // 2 KB
  u16* WqT = (u16*)(ws + 256 + 4096);              // 1536x512 bf16
  u16* WoT = WqT + (size_t)QKV_COLS * DD;          // 512x512 bf16
  u16* scratch = WoT + (size_t)DD * DD;
  const size_t fixed = 256 + 4096 + (size_t)QKV_COLS * DD * 2 + (size_t)DD * DD * 2;
  const size_t ws_avail = (ws_size > fixed) ? ws_size - fixed : 0;

  // per chunk: xb rows*1024 + qkv rows*3072 + attno rows*1024 = 5120 B/row
  const size_t per_row = 5120;
  int chunk_rows = M_TOTAL;
  while ((size_t)chunk_rows * per_row > ws_avail && chunk_rows > 256) chunk_rows >>= 1;
  const int nchunks = M_TOTAL / chunk_rows;

  u16* xb    = scratch;                                   // chunk x 512  bf16
  u16* qkv   = xb  + (size_t)chunk_rows * DD;             // chunk x 1536 bf16
  u16* attno = qkv + (size_t)chunk_rows * QKV_COLS;       // chunk x 512  bf16

  sniff_kernel<<<1, 256, 0, stream>>>((const u16*)x_raw, flag);
  rot_table_kernel<<<1, 256, 0, stream>>>(cosv, sinv);
  cast_wt_kernel<<<(QKV_COLS * DD) / 256, 256, 0, stream>>>(W_qkv, WqT, DD, QKV_COLS, flag);
  cast_wt_kernel<<<(DD * DD) / 256, 256, 0, stream>>>(W_out, WoT, DD, DD, flag);

  for (int c = 0; c < nchunks; ++c) {
    const int bs0 = c * (chunk_rows / NTOK);
    const size_t eoff = (size_t)c * chunk_rows * DD;   // element offset in x / out

    cast_x_kernel<<<(int)(((size_t)chunk_rows * DD) / 1024), 256, 0, stream>>>(
        x_raw, xb, eoff, flag);

    {  // 1) qkv = xb @ WqT^T  (256x256 8-phase)
      dim3 grid((chunk_rows / 256) * (QKV_COLS / 256));
      gemm_mfma_bt256<0><<<grid, 512, 0, stream>>>(xb, WqT, (void*)qkv, 0,
                                                   chunk_rows, QKV_COLS, DD, flag);
    }
    {  // 2) attention: one wave per (bsl, h), 4 waves per block
      dim3 grid(((chunk_rows / NTOK) * HH) / 4);
      attn_kernel<<<grid, 256, 0, stream>>>(qkv, pos_bias, maskp, attno, bs0,
                                            cosv, sinv, flag);
    }
    {  // 3) out = attno @ WoT^T  (fp32 out when flag=1, else bf16)
      dim3 grid((chunk_rows / 256) * (DD / 256));
      gemm_mfma_bt256<1><<<grid, 512, 0, stream>>>(attno, WoT, d_out, eoff,
                                                   chunk_rows, DD, DD, flag);
    }
  }
}